// Round 5
// baseline (106.175 us; speedup 1.0000x reference)
//
#include <hip/hip_runtime.h>
#include <math.h>

namespace {

constexpr int Bsz   = 16384;
constexpr int T     = 200;
constexpr int F     = 4;
constexpr int H     = 10;
constexpr int HP    = 16;   // hidden padded: 8 lanes x 2 units
constexpr int BLOCK = 256;

// tanh(x) = 1 - 2/(exp(2x)+1); saturates correctly to +/-1 for |x| large.
__device__ __forceinline__ float fast_tanh(float x) {
  float e = exp2f(x * 2.8853900817779268f);   // exp(2x) via v_exp_f32
  return 1.0f - 2.0f * __builtin_amdgcn_rcpf(e + 1.0f);
}

__device__ __forceinline__ float fast_sigmoid(float x) {
  float e = exp2f(x * -1.4426950408889634f);  // exp(-x)
  return __builtin_amdgcn_rcpf(1.0f + e);
}

// Broadcast sub-lane J's value to all lanes of each 8-lane group.
// ds_swizzle BitMode: new_lane = ((lane & and) | or) ^ xor; and=0x18 keeps the
// 8-group id, or=J selects the source sub-lane. (Encoding per cdna4_isa.md §6.)
template <int J>
__device__ __forceinline__ float bcast8(float v) {
  return __int_as_float(
      __builtin_amdgcn_ds_swizzle(__float_as_int(v), (J << 5) | 0x18));
}

// Pin a value into a VGPR; volatile asm can't be duplicated/sunk, so the
// compiler cannot re-load it inside the t-loop (rounds 1-3 failure mode).
#define PIN(v) asm volatile("" : "+v"(v))

__global__ __launch_bounds__(BLOCK, 2) void rnn2_oct(
    const float* __restrict__ x,
    const float* __restrict__ W_ih0, const float* __restrict__ W_hh0,
    const float* __restrict__ b_ih0, const float* __restrict__ b_hh0,
    const float* __restrict__ W_ih1, const float* __restrict__ W_hh1,
    const float* __restrict__ b_ih1, const float* __restrict__ b_hh1,
    const float* __restrict__ W_fc, const float* __restrict__ b_fc,
    float* __restrict__ out) {
  // FC weights in LDS, padded to HP floats per timestep (pad = 0).
  __shared__ float s_wfc[T * HP];
  for (int i = threadIdx.x; i < T * HP; i += BLOCK) {
    int t = i >> 4, u = i & 15;
    s_wfc[i] = (u < H) ? W_fc[t * H + u] : 0.0f;
  }
  __syncthreads();

  const int g  = blockIdx.x * BLOCK + threadIdx.x;
  const int b  = g >> 3;        // batch element
  const int r  = g & 7;         // sub-lane in 8-group
  const int uA = r;             // first unit  (always real: r <= 7 < 10)
  const int uB = 8 + r;         // second unit (real only for r < 2)
  const bool vB = (uB < H);

  // ---- my 2 units' weights, zero-padded, pinned into VGPRs (72 floats) ----
  float wi0A[F], wh0A[H], wi1A[H], wh1A[H];
  float wi0B[F], wh0B[H], wi1B[H], wh1B[H];
  float bA0, bA1, bB0, bB1;
#pragma unroll
  for (int j = 0; j < F; ++j) {
    wi0A[j] = W_ih0[uA * F + j];              PIN(wi0A[j]);
    wi0B[j] = vB ? W_ih0[uB * F + j] : 0.0f;  PIN(wi0B[j]);
  }
#pragma unroll
  for (int j = 0; j < H; ++j) {
    wh0A[j] = W_hh0[uA * H + j];              PIN(wh0A[j]);
    wh0B[j] = vB ? W_hh0[uB * H + j] : 0.0f;  PIN(wh0B[j]);
    wi1A[j] = W_ih1[uA * H + j];              PIN(wi1A[j]);
    wi1B[j] = vB ? W_ih1[uB * H + j] : 0.0f;  PIN(wi1B[j]);
    wh1A[j] = W_hh1[uA * H + j];              PIN(wh1A[j]);
    wh1B[j] = vB ? W_hh1[uB * H + j] : 0.0f;  PIN(wh1B[j]);
  }
  bA0 = b_ih0[uA] + b_hh0[uA];               PIN(bA0);
  bB0 = vB ? (b_ih0[uB] + b_hh0[uB]) : 0.0f; PIN(bB0);
  bA1 = b_ih1[uA] + b_hh1[uA];               PIN(bA1);
  bB1 = vB ? (b_ih1[uB] + b_hh1[uB]) : 0.0f; PIN(bB1);

  const float4* __restrict__ xrow =
      reinterpret_cast<const float4*>(x + (size_t)b * (T * F));

  float h0b[H], h1b[H];   // full broadcast h-vectors (units 0..9)
#pragma unroll
  for (int j = 0; j < H; ++j) { h0b[j] = 0.0f; h1b[j] = 0.0f; }
  float acc = 0.0f;

  float4 xv = xrow[0];
#pragma unroll 1
  for (int t = 0; t < T; ++t) {
    float4 xn = (t + 1 < T) ? xrow[t + 1] : xv;  // software prefetch

    // FC weights for this step — issued ~200 cycles before use.
    float fA = s_wfc[t * HP + uA];
    float fB = s_wfc[t * HP + uB];

    // ---- layer 0, my 2 units ----
    float sA = bA0, sB = bB0;
    sA = fmaf(wi0A[0], xv.x, sA);  sB = fmaf(wi0B[0], xv.x, sB);
    sA = fmaf(wi0A[1], xv.y, sA);  sB = fmaf(wi0B[1], xv.y, sB);
    sA = fmaf(wi0A[2], xv.z, sA);  sB = fmaf(wi0B[2], xv.z, sB);
    sA = fmaf(wi0A[3], xv.w, sA);  sB = fmaf(wi0B[3], xv.w, sB);
#pragma unroll
    for (int j = 0; j < H; ++j) {
      sA = fmaf(wh0A[j], h0b[j], sA);
      sB = fmaf(wh0B[j], h0b[j], sB);
    }
    float mA = fast_tanh(sA), mB = fast_tanh(sB);

    // broadcast new h0 across the 8-group: units 0..7 live in mA, 8..9 in mB
    h0b[0] = bcast8<0>(mA); h0b[1] = bcast8<1>(mA);
    h0b[2] = bcast8<2>(mA); h0b[3] = bcast8<3>(mA);
    h0b[4] = bcast8<4>(mA); h0b[5] = bcast8<5>(mA);
    h0b[6] = bcast8<6>(mA); h0b[7] = bcast8<7>(mA);
    h0b[8] = bcast8<0>(mB); h0b[9] = bcast8<1>(mB);

    // ---- layer 1, my 2 units ----
    sA = bA1; sB = bB1;
#pragma unroll
    for (int j = 0; j < H; ++j) {
      sA = fmaf(wi1A[j], h0b[j], sA);
      sB = fmaf(wi1B[j], h0b[j], sB);
    }
#pragma unroll
    for (int j = 0; j < H; ++j) {
      sA = fmaf(wh1A[j], h1b[j], sA);
      sB = fmaf(wh1B[j], h1b[j], sB);
    }
    mA = fast_tanh(sA); mB = fast_tanh(sB);

    // FC head contribution (pad units read 0 weights from LDS)
    acc = fmaf(mA, fA, acc);
    acc = fmaf(mB, fB, acc);

    // broadcast new h1 across the 8-group
    h1b[0] = bcast8<0>(mA); h1b[1] = bcast8<1>(mA);
    h1b[2] = bcast8<2>(mA); h1b[3] = bcast8<3>(mA);
    h1b[4] = bcast8<4>(mA); h1b[5] = bcast8<5>(mA);
    h1b[6] = bcast8<6>(mA); h1b[7] = bcast8<7>(mA);
    h1b[8] = bcast8<0>(mB); h1b[9] = bcast8<1>(mB);

    xv = xn;
  }

  // 8-lane reduce of the FC accumulator
  acc += __shfl_xor(acc, 1);
  acc += __shfl_xor(acc, 2);
  acc += __shfl_xor(acc, 4);
  if (r == 0) out[b] = fast_sigmoid(acc + b_fc[0]);
}

}  // namespace

extern "C" void kernel_launch(void* const* d_in, const int* in_sizes, int n_in,
                              void* d_out, int out_size, void* d_ws, size_t ws_size,
                              hipStream_t stream) {
  const float* x     = (const float*)d_in[0];
  const float* W_ih0 = (const float*)d_in[1];
  const float* W_hh0 = (const float*)d_in[2];
  const float* b_ih0 = (const float*)d_in[3];
  const float* b_hh0 = (const float*)d_in[4];
  const float* W_ih1 = (const float*)d_in[5];
  const float* W_hh1 = (const float*)d_in[6];
  const float* b_ih1 = (const float*)d_in[7];
  const float* b_hh1 = (const float*)d_in[8];
  const float* W_fc  = (const float*)d_in[9];
  const float* b_fc  = (const float*)d_in[10];
  float* out = (float*)d_out;

  dim3 grid((Bsz * 8) / BLOCK), block(BLOCK);
  hipLaunchKernelGGL(rnn2_oct, grid, block, 0, stream,
                     x, W_ih0, W_hh0, b_ih0, b_hh0,
                     W_ih1, W_hh1, b_ih1, b_hh1, W_fc, b_fc, out);
}